// Round 4
// baseline (21.757 us; speedup 1.0000x reference)
//
#include <hip/hip_runtime.h>

// Quanvolution quantum filter, collapsed analytically:
//   per 2x2 patch (t0,t1,t2,t3), with cq = cos(tq):
//     out[0] = c1*c2*c3
//     out[1] = c0*c1
//     out[2] = c0*c1*c2
//     out[3] = c0*c1*c2*c3
// Derivation: product state Ry rotations -> P(bq=1)=sin^2(tq/2); CNOT ring
// permutes basis states so each Z expectation is E[(-1)^{XOR subset}] =
// prod over subset of cos(tq).
//
// R2 lesson: keep per-instruction-dense pattern (float2 loads @8B lane
// stride, float4 store @16B lane stride). Wider-but-strided regressed.
// R3 lesson: __cosf vs cosf ~neutral -> not VALU-bound.
// R4 change: grid-stride with 2048 blocks (8/CU) + manual 2x unroll so each
// thread keeps 4 loads in flight (ILP) -> attack latency, not BW.

#define BATCH 16384
#define PATCHES 196   // 14 x 14
#define TOTAL (BATCH * PATCHES)
#define NBLOCKS 2048
#define NTHREADS (NBLOCKS * 256)   // 524288; TOTAL / NTHREADS = 6.125

__device__ __forceinline__ void process_patch(const float* __restrict__ x,
                                              float* __restrict__ out, int t) {
    int b = t / PATCHES;
    int p = t - b * PATCHES;
    int r = p / 14;
    int c = p - r * 14;

    const float* img = x + (size_t)b * 784;
    int base = r * 56 + c * 2;

    float2 top = *reinterpret_cast<const float2*>(img + base);        // t0, t1
    float2 bot = *reinterpret_cast<const float2*>(img + base + 28);   // t2, t3

    float c0 = __cosf(top.x);
    float c1 = __cosf(top.y);
    float c2 = __cosf(bot.x);
    float c3 = __cosf(bot.y);

    float4 o;
    o.y = c0 * c1;        // meas1
    o.z = o.y * c2;       // meas2
    o.w = o.z * c3;       // meas3
    o.x = c1 * c2 * c3;   // meas0

    *reinterpret_cast<float4*>(out + (size_t)t * 4) = o;
}

__global__ __launch_bounds__(256) void quanv_kernel(const float* __restrict__ x,
                                                    float* __restrict__ out) {
    const int stride = NTHREADS;
    int t = blockIdx.x * blockDim.x + threadIdx.x;
    // unrolled by 2: two independent patches in flight per iteration
    for (; t + stride < TOTAL; t += 2 * stride) {
        process_patch(x, out, t);
        process_patch(x, out, t + stride);
    }
    if (t < TOTAL) process_patch(x, out, t);
}

extern "C" void kernel_launch(void* const* d_in, const int* in_sizes, int n_in,
                              void* d_out, int out_size, void* d_ws, size_t ws_size,
                              hipStream_t stream) {
    const float* x = (const float*)d_in[0];
    float* out = (float*)d_out;
    quanv_kernel<<<NBLOCKS, 256, 0, stream>>>(x, out);
}

// Round 5
// 20.332 us; speedup vs baseline: 1.0701x; 1.0701x over previous
//
#include <hip/hip_runtime.h>

// Quanvolution quantum filter, collapsed analytically:
//   per 2x2 patch (t0,t1,t2,t3), with cq = cos(tq):
//     out = { c1*c2*c3, c0*c1, c0*c1*c2, c0*c1*c2*c3 }
// Derivation: Ry product state -> P(bq=1)=sin^2(tq/2); CNOT ring permutes
// basis states so each Z expectation = prod over an XOR-subset of cos(tq).
//
// R2 lesson: 32B-strided stores kill per-instruction cacheline density.
// R3 lesson: __cosf vs cosf ~neutral (not VALU-bound).
// R4 lesson: grid-stride/ILP neutral (not latency-bound at thread level).
// R5 experiment: make BOTH loads and stores 16B/lane unit-stride dense
// (exact m13 D2D-copy pattern, 6.29 TB/s) and re-associate patches via LDS.
//
// Geometry: image = 14 chunks x 56 floats (one patch-row each: 28 top + 28
// bottom). 448-thread block = 32 chunks = 448 float4 in = 448 patches =
// 448 float4 out; thread's input flat-float4 index == its output index.

#define F4_TOTAL (16384 * 196)   // 3,211,264 float4s in AND out
#define BLK 448                  // 7 waves; 448 = 14*32 chunks align exactly
#define NBLOCKS (F4_TOTAL / BLK) // 7168, no tail

__global__ __launch_bounds__(BLK) void quanv_kernel(const float4* __restrict__ x4,
                                                    float4* __restrict__ out4) {
    __shared__ float lds[BLK * 4];   // 7168 B
    int t = threadIdx.x;
    size_t g = (size_t)blockIdx.x * BLK + t;

    // dense 16B/lane load, identical pattern to the 6.29 TB/s copy µbench
    float4 v = x4[g];
    *reinterpret_cast<float4*>(&lds[t * 4]) = v;
    __syncthreads();

    // thread t computes patch c of block-local chunk k
    int k = t / 14;          // chunk within block (0..31)
    int c = t - k * 14;      // patch col (0..13)
    int fb = k * 56 + 2 * c;
    float2 top = *reinterpret_cast<const float2*>(&lds[fb]);        // t0,t1
    float2 bot = *reinterpret_cast<const float2*>(&lds[fb + 28]);   // t2,t3

    float c0 = __cosf(top.x);
    float c1 = __cosf(top.y);
    float c2 = __cosf(bot.x);
    float c3 = __cosf(bot.y);

    float4 o;
    o.y = c0 * c1;        // meas1
    o.z = o.y * c2;       // meas2
    o.w = o.z * c3;       // meas3
    o.x = c1 * c2 * c3;   // meas0

    // output flat-float4 index == g (chunk K*14 + c), dense 16B/lane store
    out4[g] = o;
}

extern "C" void kernel_launch(void* const* d_in, const int* in_sizes, int n_in,
                              void* d_out, int out_size, void* d_ws, size_t ws_size,
                              hipStream_t stream) {
    const float4* x4 = (const float4*)d_in[0];
    float4* out4 = (float4*)d_out;
    quanv_kernel<<<NBLOCKS, BLK, 0, stream>>>(x4, out4);
}